// Round 8
// baseline (402.400 us; speedup 1.0000x reference)
//
#include <hip/hip_runtime.h>
#include <hip/hip_bf16.h>

#define NNODES 50000
#define NEDGES 150000
#define DFEAT  512
#define HID    512
#define NCLS   47

typedef __hip_bfloat16 bf16;
typedef __attribute__((ext_vector_type(8))) short short8;
typedef __attribute__((ext_vector_type(4))) float float4v;

__device__ __forceinline__ float bfbits_lo(unsigned int w) {
    return __uint_as_float((w & 0xFFFFu) << 16);
}
__device__ __forceinline__ float bfbits_hi(unsigned int w) {
    return __uint_as_float(w & 0xFFFF0000u);
}

__device__ __forceinline__ short8 ld_f32_as_bf8(const float* p) {
    float4 u = *(const float4*)p;
    float4 v = *(const float4*)(p + 4);
    bf16 t[8];
    t[0] = __float2bfloat16(u.x); t[1] = __float2bfloat16(u.y);
    t[2] = __float2bfloat16(u.z); t[3] = __float2bfloat16(u.w);
    t[4] = __float2bfloat16(v.x); t[5] = __float2bfloat16(v.y);
    t[6] = __float2bfloat16(v.z); t[7] = __float2bfloat16(v.w);
    return *(const short8*)t;
}

// ---------------- dtype detection ----------------
__global__ void k_detect(const void* x, const void* ei, int* flags) {
    __shared__ int scnt[64], sor[64];
    int t = threadIdx.x;
    const unsigned short* xs = (const unsigned short*)x;
    int c = 0;
    for (int i = t; i < 256; i += 64) {
        unsigned int e = (xs[2 * i] >> 7) & 0xFF;
        c += (e >= 117 && e <= 130) ? 1 : 0;
    }
    const int* w = (const int*)ei;
    int o = 0;
    for (int i = 2 * t + 1; i < 512; i += 128) o |= w[i];
    scnt[t] = c; sor[t] = o;
    __syncthreads();
    if (t == 0) {
        int C = 0, O = 0;
        for (int i = 0; i < 64; i++) { C += scnt[i]; O |= sor[i]; }
        flags[0] = (C > 128) ? 1 : 0;
        flags[1] = (O == 0) ? 1 : 0;
    }
}

__device__ __forceinline__ int eidx(const void* ei, int half, int e, int is64) {
    if (is64) return (int)((const long long*)ei)[(size_t)half * NEDGES + e];
    return ((const int*)ei)[half * NEDGES + e];
}

__global__ void k_zero32(unsigned int* p, size_t n) {
    size_t i = (size_t)blockIdx.x * blockDim.x + threadIdx.x;
    if (i < n) p[i] = 0u;
}

// ---------------- one merged weight-prep kernel ----------------
// ranges: [0, 262144) -> W1T ; [262144, 294912) -> W2T ; then b1 (512), b2 (47)
__global__ void k_cvt_all(const void* W1, const void* b1, const void* W2, const void* b2,
                          bf16* W1T, bf16* W2T, float* b1c, float* b2c,
                          const int* flags) {
    int i = blockIdx.x * blockDim.x + threadIdx.x;
    int isb = flags[0];
    if (i < DFEAT * HID) {
        int k = i / HID, n = i % HID;
        float v = isb ? __bfloat162float(((const bf16*)W1)[i]) : ((const float*)W1)[i];
        W1T[(size_t)n * DFEAT + k] = __float2bfloat16(v);
        return;
    }
    i -= DFEAT * HID;
    if (i < 64 * HID) {
        int n = i / HID, k = i % HID;
        float v = 0.0f;
        if (n < NCLS) {
            size_t idx = (size_t)k * NCLS + n;
            v = isb ? __bfloat162float(((const bf16*)W2)[idx]) : ((const float*)W2)[idx];
        }
        W2T[(size_t)n * HID + k] = __float2bfloat16(v);
        return;
    }
    i -= 64 * HID;
    if (i < HID) {
        b1c[i] = isb ? __bfloat162float(((const bf16*)b1)[i]) : ((const float*)b1)[i];
        return;
    }
    i -= HID;
    if (i < 64) {
        float v = 0.0f;
        if (i < NCLS) v = isb ? __bfloat162float(((const bf16*)b2)[i]) : ((const float*)b2)[i];
        b2c[i] = v;
    }
}

// ---------------- graph structure ----------------
__global__ void k_count(const void* ei, int* cnt, const int* flags) {
    int e = blockIdx.x * blockDim.x + threadIdx.x;
    if (e >= NEDGES) return;
    atomicAdd(&cnt[eidx(ei, 1, e, flags[1])], 1);
}

__global__ __launch_bounds__(256) void k_scan_part(const int* cnt, int* part) {
    __shared__ int s[256];
    int i = blockIdx.x * 256 + threadIdx.x;
    s[threadIdx.x] = (i < NNODES) ? cnt[i] : 0;
    __syncthreads();
    for (int off = 128; off > 0; off >>= 1) {
        if (threadIdx.x < off) s[threadIdx.x] += s[threadIdx.x + off];
        __syncthreads();
    }
    if (threadIdx.x == 0) part[blockIdx.x] = s[0];
}

__global__ __launch_bounds__(256) void k_scan_off(int* part, int n) {
    __shared__ int s[256];
    int v = (threadIdx.x < n) ? part[threadIdx.x] : 0;
    s[threadIdx.x] = v;
    __syncthreads();
    for (int off = 1; off < 256; off <<= 1) {
        int t = (threadIdx.x >= off) ? s[threadIdx.x - off] : 0;
        __syncthreads();
        s[threadIdx.x] += t;
        __syncthreads();
    }
    if (threadIdx.x < n) part[threadIdx.x] = s[threadIdx.x] - v;
}

// also computes dinv (folded in to save a launch)
__global__ __launch_bounds__(256) void k_scan_fin(const int* cnt, const int* part,
                                                  int* rowptr, int* cursor, float* dinv) {
    __shared__ int s[256];
    int i = blockIdx.x * 256 + threadIdx.x;
    int v = (i < NNODES) ? cnt[i] : 0;
    s[threadIdx.x] = v;
    __syncthreads();
    for (int off = 1; off < 256; off <<= 1) {
        int t = (threadIdx.x >= off) ? s[threadIdx.x - off] : 0;
        __syncthreads();
        s[threadIdx.x] += t;
        __syncthreads();
    }
    int incl = s[threadIdx.x] + part[blockIdx.x];
    if (i < NNODES) {
        rowptr[i + 1] = incl;
        cursor[i] = incl - v;
        dinv[i] = rsqrtf(1.0f + (float)v);
    }
    if (i == 0) rowptr[0] = 0;
}

__global__ void k_fill(const void* ei, int* cursor, int* csr_src, const int* flags) {
    int e = blockIdx.x * blockDim.x + threadIdx.x;
    if (e >= NEDGES) return;
    int is64 = flags[1];
    int v = eidx(ei, 1, e, is64);
    int u = eidx(ei, 0, e, is64);
    int pos = atomicAdd(&cursor[v], 1);
    csr_src[pos] = u;
}

// ============ GEMM1 v5: LDS-free, barrier-free register MFMA GEMM ============
// Block = 128 rows x 128 cols, 4 waves, wave tile 32x128. A and B fragments are
// loaded DIRECTLY from global (quad lanes read consecutive 16B -> 64B-coalesced,
// L2-served). No LDS, no barriers: every wave free-runs; compiler pipelines
// loads across MFMAs via vmcnt. XCD remap keeps a row-region's 4 col-tiles on
// one XCD so x rows are HBM-fetched once (round-6 verified: FETCH 201->55 MB).
__global__ __launch_bounds__(256) void k_gemm1_v5(
    const void* __restrict__ X, const bf16* __restrict__ W1T,
    bf16* __restrict__ h1, const int* __restrict__ flags,
    int rows_per_xcd, int n_row_tiles) {
    const int b = blockIdx.x;
    const int xcd = b & 7, s = b >> 3;
    const int col_t = s & 3, lr = s >> 2;
    const int row_t = xcd * rows_per_xcd + lr;
    if (row_t >= n_row_tiles) return;
    const int row0 = row_t * 128;
    const int gc0 = col_t * 128;
    const int wave = threadIdx.x >> 6, lane = threadIdx.x & 63;
    const int frow = lane & 15, quad = lane >> 4;
    const int wrow0 = row0 + wave * 32;
    const int isb = flags[0];

    int gr0 = wrow0 + frow;      if (gr0 >= NNODES) gr0 = NNODES - 1;
    int gr1 = wrow0 + 16 + frow; if (gr1 >= NNODES) gr1 = NNODES - 1;

    const bf16* bcol[8];
#pragma unroll
    for (int j = 0; j < 8; ++j)
        bcol[j] = W1T + (size_t)(gc0 + j * 16 + frow) * DFEAT + quad * 8;

    float4v acc[2][8];
#pragma unroll
    for (int i = 0; i < 2; i++)
#pragma unroll
        for (int j = 0; j < 8; j++) acc[i][j] = (float4v){0.f, 0.f, 0.f, 0.f};

    if (isb) {
        const bf16* xb = (const bf16*)X;
        const bf16* ar0 = xb + (size_t)gr0 * DFEAT + quad * 8;
        const bf16* ar1 = xb + (size_t)gr1 * DFEAT + quad * 8;
#pragma unroll 2
        for (int ks = 0; ks < 16; ++ks) {
            const int ko = ks * 32;
            short8 a0 = *(const short8*)(ar0 + ko);
            short8 a1 = *(const short8*)(ar1 + ko);
#pragma unroll
            for (int j = 0; j < 8; ++j) {
                short8 bb = *(const short8*)(bcol[j] + ko);
                acc[0][j] = __builtin_amdgcn_mfma_f32_16x16x32_bf16(a0, bb, acc[0][j], 0, 0, 0);
                acc[1][j] = __builtin_amdgcn_mfma_f32_16x16x32_bf16(a1, bb, acc[1][j], 0, 0, 0);
            }
        }
    } else {
        const float* xf = (const float*)X;
        const float* ar0 = xf + (size_t)gr0 * DFEAT + quad * 8;
        const float* ar1 = xf + (size_t)gr1 * DFEAT + quad * 8;
        for (int ks = 0; ks < 16; ++ks) {
            const int ko = ks * 32;
            short8 a0 = ld_f32_as_bf8(ar0 + ko);
            short8 a1 = ld_f32_as_bf8(ar1 + ko);
#pragma unroll
            for (int j = 0; j < 8; ++j) {
                short8 bb = *(const short8*)(bcol[j] + ko);
                acc[0][j] = __builtin_amdgcn_mfma_f32_16x16x32_bf16(a0, bb, acc[0][j], 0, 0, 0);
                acc[1][j] = __builtin_amdgcn_mfma_f32_16x16x32_bf16(a1, bb, acc[1][j], 0, 0, 0);
            }
        }
    }
#pragma unroll
    for (int i = 0; i < 2; i++) {
#pragma unroll
        for (int r = 0; r < 4; r++) {
            int grow = wrow0 + i * 16 + quad * 4 + r;
            if (grow < NNODES) {
#pragma unroll
                for (int j = 0; j < 8; j++)
                    h1[(size_t)grow * HID + gc0 + j * 16 + frow] =
                        __float2bfloat16(acc[i][j][r]);
            }
        }
    }
}

// ============ GEMM2 v5: LDS-free h2[50000x47] = a1 @ W2 ============
// Block = 128 rows x 64 cols (padded from 47), 4 waves, wave tile 32x64.
// W2T (64 KB) is L2-broadcast to every block.
__global__ __launch_bounds__(256) void k_gemm2_v5(
    const bf16* __restrict__ A, const bf16* __restrict__ W2T,
    float* __restrict__ h2) {
    const int wave = threadIdx.x >> 6, lane = threadIdx.x & 63;
    const int frow = lane & 15, quad = lane >> 4;
    const int wrow0 = blockIdx.x * 128 + wave * 32;

    int gr0 = wrow0 + frow;      if (gr0 >= NNODES) gr0 = NNODES - 1;
    int gr1 = wrow0 + 16 + frow; if (gr1 >= NNODES) gr1 = NNODES - 1;
    const bf16* ar0 = A + (size_t)gr0 * HID + quad * 8;
    const bf16* ar1 = A + (size_t)gr1 * HID + quad * 8;
    const bf16* bcol[4];
#pragma unroll
    for (int j = 0; j < 4; ++j)
        bcol[j] = W2T + (size_t)(j * 16 + frow) * HID + quad * 8;

    float4v acc[2][4];
#pragma unroll
    for (int i = 0; i < 2; i++)
#pragma unroll
        for (int j = 0; j < 4; j++) acc[i][j] = (float4v){0.f, 0.f, 0.f, 0.f};

#pragma unroll 2
    for (int ks = 0; ks < 16; ++ks) {
        const int ko = ks * 32;
        short8 a0 = *(const short8*)(ar0 + ko);
        short8 a1 = *(const short8*)(ar1 + ko);
#pragma unroll
        for (int j = 0; j < 4; ++j) {
            short8 bb = *(const short8*)(bcol[j] + ko);
            acc[0][j] = __builtin_amdgcn_mfma_f32_16x16x32_bf16(a0, bb, acc[0][j], 0, 0, 0);
            acc[1][j] = __builtin_amdgcn_mfma_f32_16x16x32_bf16(a1, bb, acc[1][j], 0, 0, 0);
        }
    }
#pragma unroll
    for (int i = 0; i < 2; i++) {
#pragma unroll
        for (int r = 0; r < 4; r++) {
            int grow = wrow0 + i * 16 + quad * 4 + r;
            if (grow < NNODES) {
#pragma unroll
                for (int j = 0; j < 4; j++) {
                    int col = j * 16 + frow;
                    if (col < NCLS)
                        h2[(size_t)grow * NCLS + col] = acc[i][j][r];
                }
            }
        }
    }
}

// ---------------- layer1 aggregation: wave per node, uint4, csr prefetch ----------
__global__ __launch_bounds__(256) void k_agg1_512(const bf16* __restrict__ h1c,
                                                  const int* __restrict__ rowptr,
                                                  const int* __restrict__ csr_src,
                                                  const float* __restrict__ dinv,
                                                  const float* __restrict__ b1c,
                                                  bf16* __restrict__ a1c) {
    int v = blockIdx.x * 4 + (threadIdx.x >> 6);
    int lane = threadIdx.x & 63;
    if (v >= NNODES) return;
    int d8 = lane * 8;
    float dv = dinv[v];
    float s2 = dv * dv;
    uint4 w = *(const uint4*)(h1c + (size_t)v * 512 + d8);
    float a0 = s2 * bfbits_lo(w.x), a1 = s2 * bfbits_hi(w.x);
    float a2 = s2 * bfbits_lo(w.y), a3 = s2 * bfbits_hi(w.y);
    float a4 = s2 * bfbits_lo(w.z), a5 = s2 * bfbits_hi(w.z);
    float a6 = s2 * bfbits_lo(w.w), a7 = s2 * bfbits_hi(w.w);
    int p = rowptr[v], pend = rowptr[v + 1];
    int u_nxt = (p < pend) ? csr_src[p] : 0;
    for (; p < pend;) {
        int u = u_nxt;
        ++p;
        u_nxt = (p < pend) ? csr_src[p] : 0;
        float nw = dinv[u] * dv;
        uint4 q = *(const uint4*)(h1c + (size_t)u * 512 + d8);
        a0 += nw * bfbits_lo(q.x); a1 += nw * bfbits_hi(q.x);
        a2 += nw * bfbits_lo(q.y); a3 += nw * bfbits_hi(q.y);
        a4 += nw * bfbits_lo(q.z); a5 += nw * bfbits_hi(q.z);
        a6 += nw * bfbits_lo(q.w); a7 += nw * bfbits_hi(q.w);
    }
    const float* bb = b1c + d8;
    a0 += bb[0]; a1 += bb[1]; a2 += bb[2]; a3 += bb[3];
    a4 += bb[4]; a5 += bb[5]; a6 += bb[6]; a7 += bb[7];
    bf16 o[8];
    o[0] = __float2bfloat16(a0 > 0.f ? a0 : 0.f);
    o[1] = __float2bfloat16(a1 > 0.f ? a1 : 0.f);
    o[2] = __float2bfloat16(a2 > 0.f ? a2 : 0.f);
    o[3] = __float2bfloat16(a3 > 0.f ? a3 : 0.f);
    o[4] = __float2bfloat16(a4 > 0.f ? a4 : 0.f);
    o[5] = __float2bfloat16(a5 > 0.f ? a5 : 0.f);
    o[6] = __float2bfloat16(a6 > 0.f ? a6 : 0.f);
    o[7] = __float2bfloat16(a7 > 0.f ? a7 : 0.f);
    *(uint4*)(a1c + (size_t)v * 512 + d8) = *(uint4*)o;
}

// ---------------- layer2 aggregation + bias -> out ----------------
__global__ __launch_bounds__(256) void k_agg2(const float* __restrict__ h2,
                                              const int* __restrict__ rowptr,
                                              const int* __restrict__ csr_src,
                                              const float* __restrict__ dinv,
                                              const float* __restrict__ b2c,
                                              void* out, const int* flags) {
    int v = blockIdx.x * 4 + (threadIdx.x >> 6);
    int d = threadIdx.x & 63;
    if (v >= NNODES || d >= NCLS) return;
    float dv = dinv[v];
    float acc = dv * dv * h2[(size_t)v * NCLS + d];
    int pend = rowptr[v + 1];
    for (int p = rowptr[v]; p < pend; ++p) {
        int u = csr_src[p];
        acc += dinv[u] * dv * h2[(size_t)u * NCLS + d];
    }
    acc += b2c[d];
    size_t o = (size_t)v * NCLS + d;
    if (flags[0]) ((bf16*)out)[o] = __float2bfloat16(acc);
    else          ((float*)out)[o] = acc;
}

extern "C" void kernel_launch(void* const* d_in, const int* in_sizes, int n_in,
                              void* d_out, int out_size, void* d_ws, size_t ws_size,
                              hipStream_t stream) {
    const void* x  = d_in[0];
    const void* ei = d_in[1];
    const void* W1 = d_in[2];
    const void* b1 = d_in[3];
    const void* W2 = d_in[4];
    const void* b2 = d_in[5];

    char* base = (char*)d_ws;
    auto alloc = [&](size_t bytes) -> char* {
        char* p = base;
        base += (bytes + 255) & ~(size_t)255;
        return p;
    };
    int*   flags  = (int*)alloc(64);
    int*   cnt    = (int*)alloc(sizeof(int) * NNODES);
    int*   part   = (int*)alloc(sizeof(int) * 256);
    int*   rowptr = (int*)alloc(sizeof(int) * (NNODES + 1));
    int*   cursor = (int*)alloc(sizeof(int) * NNODES);
    int*   csr    = (int*)alloc(sizeof(int) * NEDGES);
    float* dinv   = (float*)alloc(sizeof(float) * NNODES);
    bf16*  W1T    = (bf16*)alloc(sizeof(bf16) * DFEAT * HID);
    float* b1c    = (float*)alloc(sizeof(float) * HID);
    bf16*  W2T    = (bf16*)alloc(sizeof(bf16) * 64 * HID);
    float* b2c    = (float*)alloc(sizeof(float) * 64);
    float* h2     = (float*)alloc(sizeof(float) * (size_t)NNODES * NCLS);
    bf16*  h1     = (bf16*)alloc(sizeof(bf16) * (size_t)NNODES * HID);
    bf16*  a1     = (bf16*)alloc(sizeof(bf16) * (size_t)NNODES * HID);

    k_detect<<<1, 64, 0, stream>>>(x, ei, flags);
    k_zero32<<<(NNODES + 255) / 256, 256, 0, stream>>>((unsigned int*)cnt, NNODES);

    const int cvt_total = DFEAT * HID + 64 * HID + HID + 64;
    k_cvt_all<<<(cvt_total + 255) / 256, 256, 0, stream>>>(W1, b1, W2, b2, W1T, W2T,
                                                           b1c, b2c, flags);

    k_count<<<(NEDGES + 255) / 256, 256, 0, stream>>>(ei, cnt, flags);
    const int nsb = (NNODES + 255) / 256;  // 196
    k_scan_part<<<nsb, 256, 0, stream>>>(cnt, part);
    k_scan_off<<<1, 256, 0, stream>>>(part, nsb);
    k_scan_fin<<<nsb, 256, 0, stream>>>(cnt, part, rowptr, cursor, dinv);
    k_fill<<<(NEDGES + 255) / 256, 256, 0, stream>>>(ei, cursor, csr, flags);

    // GEMM1: 391 row-tiles(128) x 4 col-tiles(128), XCD-remapped
    const int n_row_tiles = (NNODES + 127) / 128;       // 391
    const int rows_per_xcd = (n_row_tiles + 7) / 8;     // 49
    k_gemm1_v5<<<8 * rows_per_xcd * 4, 256, 0, stream>>>(x, W1T, h1, flags,
                                                         rows_per_xcd, n_row_tiles);
    k_agg1_512<<<(NNODES + 3) / 4, 256, 0, stream>>>(h1, rowptr, csr, dinv, b1c, a1);
    k_gemm2_v5<<<(NNODES + 127) / 128, 256, 0, stream>>>(a1, W2T, h2);
    k_agg2<<<(NNODES + 3) / 4, 256, 0, stream>>>(h2, rowptr, csr, dinv, b2c, d_out, flags);
}

// Round 9
// 355.029 us; speedup vs baseline: 1.1334x; 1.1334x over previous
//
#include <hip/hip_runtime.h>
#include <hip/hip_bf16.h>

#define NNODES 50000
#define NEDGES 150000
#define DFEAT  512
#define HID    512
#define NCLS   47

typedef __hip_bfloat16 bf16;
typedef __attribute__((ext_vector_type(8))) short short8;
typedef __attribute__((ext_vector_type(4))) float float4v;

typedef const __attribute__((address_space(1))) unsigned int* gas_t;
typedef __attribute__((address_space(3))) unsigned int* las_t;
__device__ __forceinline__ void load_lds16(const void* g, void* l) {
    __builtin_amdgcn_global_load_lds((gas_t)g, (las_t)l, 16, 0, 0);
}

__device__ __forceinline__ float bfbits_lo(unsigned int w) {
    return __uint_as_float((w & 0xFFFFu) << 16);
}
__device__ __forceinline__ float bfbits_hi(unsigned int w) {
    return __uint_as_float(w & 0xFFFF0000u);
}

__device__ __forceinline__ short8 ld_f32_as_bf8(const float* p) {
    float4 u = *(const float4*)p;
    float4 v = *(const float4*)(p + 4);
    bf16 t[8];
    t[0] = __float2bfloat16(u.x); t[1] = __float2bfloat16(u.y);
    t[2] = __float2bfloat16(u.z); t[3] = __float2bfloat16(u.w);
    t[4] = __float2bfloat16(v.x); t[5] = __float2bfloat16(v.y);
    t[6] = __float2bfloat16(v.z); t[7] = __float2bfloat16(v.w);
    return *(const short8*)t;
}

// ---------------- dtype detection ----------------
__global__ void k_detect(const void* x, const void* ei, int* flags) {
    __shared__ int scnt[64], sor[64];
    int t = threadIdx.x;
    const unsigned short* xs = (const unsigned short*)x;
    int c = 0;
    for (int i = t; i < 256; i += 64) {
        unsigned int e = (xs[2 * i] >> 7) & 0xFF;
        c += (e >= 117 && e <= 130) ? 1 : 0;
    }
    const int* w = (const int*)ei;
    int o = 0;
    for (int i = 2 * t + 1; i < 512; i += 128) o |= w[i];
    scnt[t] = c; sor[t] = o;
    __syncthreads();
    if (t == 0) {
        int C = 0, O = 0;
        for (int i = 0; i < 64; i++) { C += scnt[i]; O |= sor[i]; }
        flags[0] = (C > 128) ? 1 : 0;
        flags[1] = (O == 0) ? 1 : 0;
    }
}

__device__ __forceinline__ int eidx(const void* ei, int half, int e, int is64) {
    if (is64) return (int)((const long long*)ei)[(size_t)half * NEDGES + e];
    return ((const int*)ei)[half * NEDGES + e];
}

// ---------------- one merged weight-prep kernel ----------------
__global__ void k_cvt_all(const void* W1, const void* b1, const void* W2, const void* b2,
                          bf16* W1T, bf16* W2T, float* b1c, float* b2c,
                          const int* flags) {
    int i = blockIdx.x * blockDim.x + threadIdx.x;
    int isb = flags[0];
    if (i < DFEAT * HID) {
        int k = i / HID, n = i % HID;
        float v = isb ? __bfloat162float(((const bf16*)W1)[i]) : ((const float*)W1)[i];
        W1T[(size_t)n * DFEAT + k] = __float2bfloat16(v);
        return;
    }
    i -= DFEAT * HID;
    if (i < 64 * HID) {
        int n = i / HID, k = i % HID;
        float v = 0.0f;
        if (n < NCLS) {
            size_t idx = (size_t)k * NCLS + n;
            v = isb ? __bfloat162float(((const bf16*)W2)[idx]) : ((const float*)W2)[idx];
        }
        W2T[(size_t)n * HID + k] = __float2bfloat16(v);
        return;
    }
    i -= 64 * HID;
    if (i < HID) {
        b1c[i] = isb ? __bfloat162float(((const bf16*)b1)[i]) : ((const float*)b1)[i];
        return;
    }
    i -= HID;
    if (i < 64) {
        float v = 0.0f;
        if (i < NCLS) v = isb ? __bfloat162float(((const bf16*)b2)[i]) : ((const float*)b2)[i];
        b2c[i] = v;
    }
}

// ---------------- graph structure ----------------
__global__ void k_count(const void* ei, int* cnt, const int* flags) {
    int e = blockIdx.x * blockDim.x + threadIdx.x;
    if (e >= NEDGES) return;
    atomicAdd(&cnt[eidx(ei, 1, e, flags[1])], 1);
}

__global__ __launch_bounds__(256) void k_scan_part(const int* cnt, int* part) {
    __shared__ int s[256];
    int i = blockIdx.x * 256 + threadIdx.x;
    s[threadIdx.x] = (i < NNODES) ? cnt[i] : 0;
    __syncthreads();
    for (int off = 128; off > 0; off >>= 1) {
        if (threadIdx.x < off) s[threadIdx.x] += s[threadIdx.x + off];
        __syncthreads();
    }
    if (threadIdx.x == 0) part[blockIdx.x] = s[0];
}

__global__ __launch_bounds__(256) void k_scan_off(int* part, int n) {
    __shared__ int s[256];
    int v = (threadIdx.x < n) ? part[threadIdx.x] : 0;
    s[threadIdx.x] = v;
    __syncthreads();
    for (int off = 1; off < 256; off <<= 1) {
        int t = (threadIdx.x >= off) ? s[threadIdx.x - off] : 0;
        __syncthreads();
        s[threadIdx.x] += t;
        __syncthreads();
    }
    if (threadIdx.x < n) part[threadIdx.x] = s[threadIdx.x] - v;
}

__global__ __launch_bounds__(256) void k_scan_fin(const int* cnt, const int* part,
                                                  int* rowptr, int* cursor, float* dinv) {
    __shared__ int s[256];
    int i = blockIdx.x * 256 + threadIdx.x;
    int v = (i < NNODES) ? cnt[i] : 0;
    s[threadIdx.x] = v;
    __syncthreads();
    for (int off = 1; off < 256; off <<= 1) {
        int t = (threadIdx.x >= off) ? s[threadIdx.x - off] : 0;
        __syncthreads();
        s[threadIdx.x] += t;
        __syncthreads();
    }
    int incl = s[threadIdx.x] + part[blockIdx.x];
    if (i < NNODES) {
        rowptr[i + 1] = incl;
        cursor[i] = incl - v;
        dinv[i] = rsqrtf(1.0f + (float)v);
    }
    if (i == 0) rowptr[0] = 0;
}

__global__ void k_fill(const void* ei, int* cursor, int* csr_src, const int* flags) {
    int e = blockIdx.x * blockDim.x + threadIdx.x;
    if (e >= NEDGES) return;
    int is64 = flags[1];
    int v = eidx(ei, 1, e, is64);
    int u = eidx(ei, 0, e, is64);
    int pos = atomicAdd(&cursor[v], 1);
    csr_src[pos] = u;
}

// ============ GEMM1 v6: occupancy-first. A direct-global, B-only LDS (8 KB) ===
// Block = 128 rows x 64 cols, 4 waves, wave tile 32x64 (acc 2x4 = 32 VGPR).
// B tile (64 cols x BK=64, 8 KB) staged per K-iter via global_load_lds with
// XOR swizzle; A fragments are per-wave private rows read straight from global
// (64B-coalesced per quad, XCD-local L2). LDS 8 KB + small acc -> high ceiling.
// XCD remap (R6-verified): 8 col-tiles of a row region on one XCD.
__global__ __launch_bounds__(256, 6) void k_gemm1_v6(
    const void* __restrict__ X, const bf16* __restrict__ W1T,
    bf16* __restrict__ h1, const int* __restrict__ flags,
    int rows_per_xcd, int n_row_tiles) {
    __shared__ bf16 Bs[64 * 64];  // [col][pos] 8 KB
    const int b = blockIdx.x;
    const int xcd = b & 7, s = b >> 3;
    const int col_t = s & 7, lr = s >> 3;
    const int row_t = xcd * rows_per_xcd + lr;
    if (row_t >= n_row_tiles) return;
    const int row0 = row_t * 128;
    const int gc0 = col_t * 64;
    const int wave = threadIdx.x >> 6, lane = threadIdx.x & 63;
    const int frow = lane & 15, quad = lane >> 4;
    const int wrow0 = row0 + wave * 32;
    const int isb = flags[0];

    int gr0 = wrow0 + frow;      if (gr0 >= NNODES) gr0 = NNODES - 1;
    int gr1 = wrow0 + 16 + frow; if (gr1 >= NNODES) gr1 = NNODES - 1;

    // B staging lane mapping: instr t covers col group g8 = wave*2+t (8 cols);
    // col = g8*8 + (lane>>3), dst pos = lane&7, content chunk ck = pos ^ (col&7).
    const int st_col0 = (lane >> 3);
    const int st_pos = lane & 7;

    float4v acc[2][4];
#pragma unroll
    for (int i = 0; i < 2; i++)
#pragma unroll
        for (int j = 0; j < 4; j++) acc[i][j] = (float4v){0.f, 0.f, 0.f, 0.f};

    for (int k0 = 0; k0 < DFEAT; k0 += 64) {
        __syncthreads();
#pragma unroll
        for (int t = 0; t < 2; ++t) {
            int g8 = wave * 2 + t;
            int col = g8 * 8 + st_col0;
            int ck = st_pos ^ (col & 7);
            load_lds16(W1T + (size_t)(gc0 + col) * DFEAT + k0 + ck * 8, &Bs[g8 * 8 * 64]);
        }
        __syncthreads();
#pragma unroll
        for (int ki = 0; ki < 2; ++ki) {
            const int ko = k0 + ki * 32;
            short8 a0, a1;
            if (isb) {
                const bf16* xb = (const bf16*)X;
                a0 = *(const short8*)(xb + (size_t)gr0 * DFEAT + ko + quad * 8);
                a1 = *(const short8*)(xb + (size_t)gr1 * DFEAT + ko + quad * 8);
            } else {
                const float* xf = (const float*)X;
                a0 = ld_f32_as_bf8(xf + (size_t)gr0 * DFEAT + ko + quad * 8);
                a1 = ld_f32_as_bf8(xf + (size_t)gr1 * DFEAT + ko + quad * 8);
            }
#pragma unroll
            for (int j = 0; j < 4; ++j) {
                int col = j * 16 + frow;
                int cc = ki * 4 + quad;
                int pos = (cc & ~7) | ((cc & 7) ^ (col & 7));
                short8 bb = *(const short8*)&Bs[col * 64 + pos * 8];
                acc[0][j] = __builtin_amdgcn_mfma_f32_16x16x32_bf16(a0, bb, acc[0][j], 0, 0, 0);
                acc[1][j] = __builtin_amdgcn_mfma_f32_16x16x32_bf16(a1, bb, acc[1][j], 0, 0, 0);
            }
        }
    }
#pragma unroll
    for (int i = 0; i < 2; i++) {
#pragma unroll
        for (int r = 0; r < 4; r++) {
            int grow = wrow0 + i * 16 + quad * 4 + r;
            if (grow < NNODES) {
#pragma unroll
                for (int j = 0; j < 4; j++)
                    h1[(size_t)grow * HID + gc0 + j * 16 + frow] =
                        __float2bfloat16(acc[i][j][r]);
            }
        }
    }
}

// ============ GEMM2 v5: LDS-free h2[50000x47] = a1 @ W2 ============
__global__ __launch_bounds__(256) void k_gemm2_v5(
    const bf16* __restrict__ A, const bf16* __restrict__ W2T,
    float* __restrict__ h2) {
    const int wave = threadIdx.x >> 6, lane = threadIdx.x & 63;
    const int frow = lane & 15, quad = lane >> 4;
    const int wrow0 = blockIdx.x * 128 + wave * 32;

    int gr0 = wrow0 + frow;      if (gr0 >= NNODES) gr0 = NNODES - 1;
    int gr1 = wrow0 + 16 + frow; if (gr1 >= NNODES) gr1 = NNODES - 1;
    const bf16* ar0 = A + (size_t)gr0 * HID + quad * 8;
    const bf16* ar1 = A + (size_t)gr1 * HID + quad * 8;
    const bf16* bcol[4];
#pragma unroll
    for (int j = 0; j < 4; ++j)
        bcol[j] = W2T + (size_t)(j * 16 + frow) * HID + quad * 8;

    float4v acc[2][4];
#pragma unroll
    for (int i = 0; i < 2; i++)
#pragma unroll
        for (int j = 0; j < 4; j++) acc[i][j] = (float4v){0.f, 0.f, 0.f, 0.f};

#pragma unroll 2
    for (int ks = 0; ks < 16; ++ks) {
        const int ko = ks * 32;
        short8 a0 = *(const short8*)(ar0 + ko);
        short8 a1 = *(const short8*)(ar1 + ko);
#pragma unroll
        for (int j = 0; j < 4; ++j) {
            short8 bb = *(const short8*)(bcol[j] + ko);
            acc[0][j] = __builtin_amdgcn_mfma_f32_16x16x32_bf16(a0, bb, acc[0][j], 0, 0, 0);
            acc[1][j] = __builtin_amdgcn_mfma_f32_16x16x32_bf16(a1, bb, acc[1][j], 0, 0, 0);
        }
    }
#pragma unroll
    for (int i = 0; i < 2; i++) {
#pragma unroll
        for (int r = 0; r < 4; r++) {
            int grow = wrow0 + i * 16 + quad * 4 + r;
            if (grow < NNODES) {
#pragma unroll
                for (int j = 0; j < 4; j++) {
                    int col = j * 16 + frow;
                    if (col < NCLS)
                        h2[(size_t)grow * NCLS + col] = acc[i][j][r];
                }
            }
        }
    }
}

// ---------------- layer1 aggregation: wave per node, uint4, csr prefetch ----------
__global__ __launch_bounds__(256) void k_agg1_512(const bf16* __restrict__ h1c,
                                                  const int* __restrict__ rowptr,
                                                  const int* __restrict__ csr_src,
                                                  const float* __restrict__ dinv,
                                                  const float* __restrict__ b1c,
                                                  bf16* __restrict__ a1c) {
    int v = blockIdx.x * 4 + (threadIdx.x >> 6);
    int lane = threadIdx.x & 63;
    if (v >= NNODES) return;
    int d8 = lane * 8;
    float dv = dinv[v];
    float s2 = dv * dv;
    uint4 w = *(const uint4*)(h1c + (size_t)v * 512 + d8);
    float a0 = s2 * bfbits_lo(w.x), a1 = s2 * bfbits_hi(w.x);
    float a2 = s2 * bfbits_lo(w.y), a3 = s2 * bfbits_hi(w.y);
    float a4 = s2 * bfbits_lo(w.z), a5 = s2 * bfbits_hi(w.z);
    float a6 = s2 * bfbits_lo(w.w), a7 = s2 * bfbits_hi(w.w);
    int p = rowptr[v], pend = rowptr[v + 1];
    int u_nxt = (p < pend) ? csr_src[p] : 0;
    for (; p < pend;) {
        int u = u_nxt;
        ++p;
        u_nxt = (p < pend) ? csr_src[p] : 0;
        float nw = dinv[u] * dv;
        uint4 q = *(const uint4*)(h1c + (size_t)u * 512 + d8);
        a0 += nw * bfbits_lo(q.x); a1 += nw * bfbits_hi(q.x);
        a2 += nw * bfbits_lo(q.y); a3 += nw * bfbits_hi(q.y);
        a4 += nw * bfbits_lo(q.z); a5 += nw * bfbits_hi(q.z);
        a6 += nw * bfbits_lo(q.w); a7 += nw * bfbits_hi(q.w);
    }
    const float* bb = b1c + d8;
    a0 += bb[0]; a1 += bb[1]; a2 += bb[2]; a3 += bb[3];
    a4 += bb[4]; a5 += bb[5]; a6 += bb[6]; a7 += bb[7];
    bf16 o[8];
    o[0] = __float2bfloat16(a0 > 0.f ? a0 : 0.f);
    o[1] = __float2bfloat16(a1 > 0.f ? a1 : 0.f);
    o[2] = __float2bfloat16(a2 > 0.f ? a2 : 0.f);
    o[3] = __float2bfloat16(a3 > 0.f ? a3 : 0.f);
    o[4] = __float2bfloat16(a4 > 0.f ? a4 : 0.f);
    o[5] = __float2bfloat16(a5 > 0.f ? a5 : 0.f);
    o[6] = __float2bfloat16(a6 > 0.f ? a6 : 0.f);
    o[7] = __float2bfloat16(a7 > 0.f ? a7 : 0.f);
    *(uint4*)(a1c + (size_t)v * 512 + d8) = *(uint4*)o;
}

// ---------------- layer2 aggregation + bias -> out ----------------
__global__ __launch_bounds__(256) void k_agg2(const float* __restrict__ h2,
                                              const int* __restrict__ rowptr,
                                              const int* __restrict__ csr_src,
                                              const float* __restrict__ dinv,
                                              const float* __restrict__ b2c,
                                              void* out, const int* flags) {
    int v = blockIdx.x * 4 + (threadIdx.x >> 6);
    int d = threadIdx.x & 63;
    if (v >= NNODES || d >= NCLS) return;
    float dv = dinv[v];
    float acc = dv * dv * h2[(size_t)v * NCLS + d];
    int pend = rowptr[v + 1];
    for (int p = rowptr[v]; p < pend; ++p) {
        int u = csr_src[p];
        acc += dinv[u] * dv * h2[(size_t)u * NCLS + d];
    }
    acc += b2c[d];
    size_t o = (size_t)v * NCLS + d;
    if (flags[0]) ((bf16*)out)[o] = __float2bfloat16(acc);
    else          ((float*)out)[o] = acc;
}

extern "C" void kernel_launch(void* const* d_in, const int* in_sizes, int n_in,
                              void* d_out, int out_size, void* d_ws, size_t ws_size,
                              hipStream_t stream) {
    const void* x  = d_in[0];
    const void* ei = d_in[1];
    const void* W1 = d_in[2];
    const void* b1 = d_in[3];
    const void* W2 = d_in[4];
    const void* b2 = d_in[5];

    char* base = (char*)d_ws;
    auto alloc = [&](size_t bytes) -> char* {
        char* p = base;
        base += (bytes + 255) & ~(size_t)255;
        return p;
    };
    int*   flags  = (int*)alloc(64);
    int*   cnt    = (int*)alloc(sizeof(int) * NNODES);
    int*   part   = (int*)alloc(sizeof(int) * 256);
    int*   rowptr = (int*)alloc(sizeof(int) * (NNODES + 1));
    int*   cursor = (int*)alloc(sizeof(int) * NNODES);
    int*   csr    = (int*)alloc(sizeof(int) * NEDGES);
    float* dinv   = (float*)alloc(sizeof(float) * NNODES);
    bf16*  W1T    = (bf16*)alloc(sizeof(bf16) * DFEAT * HID);
    float* b1c    = (float*)alloc(sizeof(float) * HID);
    bf16*  W2T    = (bf16*)alloc(sizeof(bf16) * 64 * HID);
    float* b2c    = (float*)alloc(sizeof(float) * 64);
    float* h2     = (float*)alloc(sizeof(float) * (size_t)NNODES * NCLS);
    bf16*  h1     = (bf16*)alloc(sizeof(bf16) * (size_t)NNODES * HID);
    bf16*  a1     = (bf16*)alloc(sizeof(bf16) * (size_t)NNODES * HID);

    k_detect<<<1, 64, 0, stream>>>(x, ei, flags);
    hipMemsetAsync(cnt, 0, sizeof(int) * NNODES, stream);

    const int cvt_total = DFEAT * HID + 64 * HID + HID + 64;
    k_cvt_all<<<(cvt_total + 255) / 256, 256, 0, stream>>>(W1, b1, W2, b2, W1T, W2T,
                                                           b1c, b2c, flags);

    k_count<<<(NEDGES + 255) / 256, 256, 0, stream>>>(ei, cnt, flags);
    const int nsb = (NNODES + 255) / 256;  // 196
    k_scan_part<<<nsb, 256, 0, stream>>>(cnt, part);
    k_scan_off<<<1, 256, 0, stream>>>(part, nsb);
    k_scan_fin<<<nsb, 256, 0, stream>>>(cnt, part, rowptr, cursor, dinv);
    k_fill<<<(NEDGES + 255) / 256, 256, 0, stream>>>(ei, cursor, csr, flags);

    // GEMM1: 391 row-tiles(128) x 8 col-tiles(64), XCD-remapped
    const int n_row_tiles = (NNODES + 127) / 128;       // 391
    const int rows_per_xcd = (n_row_tiles + 7) / 8;     // 49
    k_gemm1_v6<<<8 * rows_per_xcd * 8, 256, 0, stream>>>(x, W1T, h1, flags,
                                                         rows_per_xcd, n_row_tiles);
    k_agg1_512<<<(NNODES + 3) / 4, 256, 0, stream>>>(h1, rowptr, csr, dinv, b1c, a1);
    k_gemm2_v5<<<(NNODES + 127) / 128, 256, 0, stream>>>(a1, W2T, h2);
    k_agg2<<<(NNODES + 3) / 4, 256, 0, stream>>>(h2, rowptr, csr, dinv, b2c, d_out, flags);
}